// Round 5
// baseline (257.840 us; speedup 1.0000x reference)
//
#include <hip/hip_runtime.h>

// Cost volume: volume[b,d,h,w] = mean_c left[b,c,h,w] * right[b,c,h,w-d], 0 for w<d.
// B=8 C=64 H=160 W=320 D=48, f32 in / f32 out.
//
// One 256-thread block per (b,h) row. Channels streamed through LDS in 8 chunks
// of 8, double-buffered (40 KB -> 4 blocks/CU, 16 waves). Staging: waves 0,1
// stage L, waves 2,3 stage R — exactly 5 x 1KB global_load_lds per wave per
// chunk, so counted s_waitcnt vmcnt(5) + raw s_barrier keeps the next chunk's
// loads in flight across barriers (never drain to 0 in the loop).
// Thread t owns one w-quad (w0 = (t%80)*4; lanes contiguous -> 16B-stride
// conflict-free ds_read_b128) x one 16-deep d-tile (d0 = (t/80)*16).
// 240 active threads of 256. 1.5 LDS bytes per FMA.

constexpr int C_ = 64, H_ = 160, W_ = 320, D_ = 48;
constexpr int HW_ = H_ * W_;            // 51200
constexpr int CK_ = 8;                  // channels per LDS chunk
constexpr int CHF = CK_ * W_;           // 2560 floats per chunk buffer
// LDS floats: [L0 @0][L1 @CHF][R0 @2*CHF][R1 @3*CHF]
// R reads may underflow by up to 48 floats (w<d diagonal): R0 underflow lands
// in L1, R1 in R0 — valid LDS, finite garbage, only feeds store-masked outputs.

typedef __attribute__((address_space(1))) unsigned int gu32;
typedef __attribute__((address_space(3))) unsigned int lu32;
typedef float f32x4 __attribute__((ext_vector_type(4)));

__device__ __forceinline__ void gload_lds16(const float* g, float* l) {
  __builtin_amdgcn_global_load_lds((const gu32*)g, (lu32*)l, 16, 0, 0);
}

__global__ __launch_bounds__(256, 2)
void corvol_kernel(const float* __restrict__ L, const float* __restrict__ R,
                   float* __restrict__ out) {
  __shared__ __align__(16) float lds[4 * CHF];   // 40960 B

  const int tid  = threadIdx.x;
  const int lane = tid & 63;
  const int wv   = tid >> 6;              // 0..3

  const int bh = blockIdx.x;              // b*H + h
  const int b  = bh / H_;
  const int h  = bh - b * H_;
  const int inbase = b * (C_ * HW_) + h * W_;

  // Staging role: waves 0,1 -> L ; waves 2,3 -> R ; 5 x 1KB segments per wave.
  const float* gb = (wv < 2 ? L : R) + inbase;
  float* const lb0 = &lds[(wv < 2 ? 0 : 2 * CHF)];
  const int seg0 = (wv & 1) * 5;          // first of this wave's 5 segments
  int off[5];                             // per-lane global float offsets (c*HW + w)
#pragma unroll
  for (int s = 0; s < 5; ++s) {
    const int f = (seg0 + s) * 256 + lane * 4;   // float index in [8][320] chunk
    const int c = f / W_;                        // 16B never straddles a row (320%4==0)
    off[s] = c * HW_ + (f - c * W_);
  }

  // thread -> (d-tile, w-quad): 80 quads x 3 d-tiles = 240 active threads
  const int q  = tid % 80;
  const int dt = tid / 80;
  const int w0 = q * 4;
  const int d0 = dt * 16;
  const bool active = (dt < 3);

  float acc[16][4];
#pragma unroll
  for (int i = 0; i < 16; ++i)
#pragma unroll
    for (int j = 0; j < 4; ++j) acc[i][j] = 0.0f;

  auto stage = [&](int ck, int p) {
    const int cb = ck * CK_ * HW_;
    float* lb = lb0 + p * CHF + seg0 * 256;
#pragma unroll
    for (int s = 0; s < 5; ++s)
      gload_lds16(gb + cb + off[s], lb + s * 256);
  };

  auto compute = [&](int p) {
    const float* Lc = &lds[p * CHF];
    const float* Rc = &lds[2 * CHF + p * CHF];
#pragma unroll
    for (int c = 0; c < CK_; ++c) {
      const f32x4 a = *(const f32x4*)(Lc + c * W_ + w0);
      const float* rp = Rc + c * W_ + (w0 - d0 - 16);  // 16B-aligned; may underflow
      float rv[20];
#pragma unroll
      for (int k = 0; k < 5; ++k) {
        const f32x4 r = *(const f32x4*)(rp + 4 * k);
        rv[4 * k + 0] = r.x; rv[4 * k + 1] = r.y;
        rv[4 * k + 2] = r.z; rv[4 * k + 3] = r.w;
      }
      const float la[4] = {a.x, a.y, a.z, a.w};
#pragma unroll
      for (int dd = 0; dd < 16; ++dd)
#pragma unroll
        for (int j = 0; j < 4; ++j)
          acc[dd][j] = fmaf(la[j], rv[16 + j - dd], acc[dd][j]);
    }
  };

  stage(0, 0);                            // 5 loads in flight

#pragma unroll 1
  for (int ck = 0; ck < 8; ++ck) {
    if (ck < 7) stage(ck + 1, (ck + 1) & 1);      // +5 loads (10 in flight)
    // wait for chunk ck's 5 loads; keep chunk ck+1's 5 in flight
    if (ck < 7) asm volatile("s_waitcnt vmcnt(5)" ::: "memory");
    else        asm volatile("s_waitcnt vmcnt(0)" ::: "memory");
    __builtin_amdgcn_sched_barrier(0);
    __builtin_amdgcn_s_barrier();                 // all waves: chunk ck is in LDS
    __builtin_amdgcn_sched_barrier(0);
    if (active) compute(ck & 1);
    if (ck < 7) {
      __builtin_amdgcn_sched_barrier(0);
      __builtin_amdgcn_s_barrier();               // WAR: buffer ck&1 free for stage(ck+2)
      __builtin_amdgcn_sched_barrier(0);
    }
  }

  if (active) {
    constexpr float sc = 1.0f / 64.0f;
    const int ob = b * (D_ * HW_) + h * W_ + w0;
#pragma unroll
    for (int dd = 0; dd < 16; ++dd) {
      const int d = d0 + dd;
      f32x4 o;
      o.x = (w0 + 0 >= d) ? acc[dd][0] * sc : 0.0f;
      o.y = (w0 + 1 >= d) ? acc[dd][1] * sc : 0.0f;
      o.z = (w0 + 2 >= d) ? acc[dd][2] * sc : 0.0f;
      o.w = (w0 + 3 >= d) ? acc[dd][3] * sc : 0.0f;
      __builtin_nontemporal_store(o, (f32x4*)(out + ob + d * HW_));
    }
  }
}

extern "C" void kernel_launch(void* const* d_in, const int* in_sizes, int n_in,
                              void* d_out, int out_size, void* d_ws, size_t ws_size,
                              hipStream_t stream) {
  const float* left  = (const float*)d_in[0];
  const float* right = (const float*)d_in[1];
  float* out = (float*)d_out;
  const int B = 8;
  dim3 grid(B * H_), block(256);
  corvol_kernel<<<grid, block, 0, stream>>>(left, right, out);
}